// Round 1
// baseline (469.451 us; speedup 1.0000x reference)
//
#include <hip/hip_runtime.h>
#include <hip/hip_bf16.h>
#include <cstdint>

#define NN 2048
#define BB 8
#define DIN 128
#define DOUT 64
#define LRELU_ALPHA 0.2f

// Kernel 1: xp = x @ W^T + b; e_src[r] = xp[r].a_src; e_dst[r] = xp[r].a_dst
// grid = (B*N)/16 blocks, 256 threads. W staged in LDS with stride 129
// (129%32==1 -> lanes d=0..63 hit banks (d+k)&31 -> 2-way aliasing = free).
__global__ __launch_bounds__(256) void gat_xp_kernel(
    const float* __restrict__ x, const float* __restrict__ W,
    const float* __restrict__ bias, const float* __restrict__ a,
    float* __restrict__ xp, float* __restrict__ e_src, float* __restrict__ e_dst)
{
    __shared__ float Wl[64 * 129];
    __shared__ float xl[16 * 128];
    const int t = threadIdx.x;
    const int d = t & 63;
    const int w = t >> 6;

    // Stage W (64x128 = 8192 floats), coalesced global reads.
    #pragma unroll
    for (int i = 0; i < 32; ++i) {
        int flat = i * 256 + t;
        int dd = flat >> 7, kk = flat & 127;
        Wl[dd * 129 + kk] = W[flat];
    }
    const int R0 = blockIdx.x * 16;
    // Stage 16 x rows (16*128 floats), coalesced.
    #pragma unroll
    for (int i = 0; i < 8; ++i) {
        int flat = i * 256 + t;
        xl[flat] = x[(size_t)R0 * DIN + flat];
    }
    const float bv = bias[d];
    const float as = a[d];          // a_src[d]
    const float ad = a[DOUT + d];   // a_dst[d]
    __syncthreads();

    // Each wave w handles rows w*4 .. w*4+3 (chunked), lane = output dim d.
    #pragma unroll
    for (int c = 0; c < 4; ++c) {
        const int r = w * 4 + c;
        const float* xr = &xl[r * DIN];   // broadcast reads (same addr all lanes)
        const float* wr = &Wl[d * 129];
        float v = bv;
        #pragma unroll
        for (int k = 0; k < DIN; ++k) v += xr[k] * wr[k];
        xp[(size_t)(R0 + r) * DOUT + d] = v;   // coalesced 256B store per wave
        // wave-reduce the two rank-1 logit dots across the 64 lanes
        float es = v * as;
        float ed = v * ad;
        #pragma unroll
        for (int off = 32; off >= 1; off >>= 1) {
            es += __shfl_xor(es, off);
            ed += __shfl_xor(ed, off);
        }
        if (d == 0) {
            e_src[R0 + r] = es;
            e_dst[R0 + r] = ed;
        }
    }
}

// Kernel 2: one block per output row (b,m). 256 threads = 4 waves.
// Pass A: stream adj row (coalesced int32), build masked leaky-relu logits in
//         LDS, block max-reduce.
// Pass B: p = exp(e - max) in LDS, block sum-reduce.
// Pass C: lane d owns output dim d; wave w accumulates n = 4j+w.
//         xp reads are 256B contiguous per wave instruction, L2-resident.
__global__ __launch_bounds__(256) void gat_attn_kernel(
    const int* __restrict__ adj, const float* __restrict__ xp,
    const float* __restrict__ e_src, const float* __restrict__ e_dst,
    float* __restrict__ out)
{
    __shared__ float e_l[NN];     // 8 KB: logits, then probabilities
    __shared__ float red[256];
    __shared__ float warr[4];
    __shared__ float sarr[4];

    const int t = threadIdx.x;
    const int bid = blockIdx.x;           // = b*N + m
    const int base = (bid >> 11) << 11;   // b*N
    const size_t adjoff = (size_t)bid * NN;
    const float s = e_src[bid];
    const float* __restrict__ edst = e_dst + base;

    // ---- Pass A: logits + max ----
    float lmax = -1e30f;
    #pragma unroll
    for (int i = 0; i < 8; ++i) {
        const int n = t + i * 256;
        const int av = adj[adjoff + n];
        float e = s + edst[n];
        e = (e > 0.f) ? e : LRELU_ALPHA * e;  // leaky_relu BEFORE mask (ref order)
        e = av ? e : -1e30f;
        e_l[n] = e;
        lmax = fmaxf(lmax, e);
    }
    #pragma unroll
    for (int off = 32; off >= 1; off >>= 1)
        lmax = fmaxf(lmax, __shfl_xor(lmax, off));
    if ((t & 63) == 0) warr[t >> 6] = lmax;
    __syncthreads();
    const float maxv = fmaxf(fmaxf(warr[0], warr[1]), fmaxf(warr[2], warr[3]));

    // ---- Pass B: exp + sum ----
    float lsum = 0.f;
    #pragma unroll
    for (int i = 0; i < 8; ++i) {
        const int n = t + i * 256;
        const float e = e_l[n];
        const float p = (e > -1e29f) ? __expf(e - maxv) : 0.f;
        e_l[n] = p;
        lsum += p;
    }
    #pragma unroll
    for (int off = 32; off >= 1; off >>= 1)
        lsum += __shfl_xor(lsum, off);
    if ((t & 63) == 0) sarr[t >> 6] = lsum;
    __syncthreads();
    const float inv = 1.f / (sarr[0] + sarr[1] + sarr[2] + sarr[3]);

    // ---- Pass C: weighted sum of xp rows ----
    const int d = t & 63;
    const int w = t >> 6;
    const float* __restrict__ xpb = xp + (size_t)base * DOUT + d;
    float acc = 0.f;
    #pragma unroll 8
    for (int j = 0; j < NN / 4; ++j) {
        const int n = j * 4 + w;
        acc += e_l[n] * xpb[(size_t)n * DOUT];  // e_l broadcast; xp 256B/wave
    }
    red[t] = acc;
    __syncthreads();
    if (t < 64) {
        const float r =
            (red[t] + red[t + 64] + red[t + 128] + red[t + 192]) * inv;
        out[(size_t)bid * DOUT + t] = r;
    }
}

extern "C" void kernel_launch(void* const* d_in, const int* in_sizes, int n_in,
                              void* d_out, int out_size, void* d_ws, size_t ws_size,
                              hipStream_t stream) {
    const float* x    = (const float*)d_in[0];
    const int*   adj  = (const int*)d_in[1];
    const float* W    = (const float*)d_in[2];
    const float* bvec = (const float*)d_in[3];
    const float* a    = (const float*)d_in[4];
    float* out = (float*)d_out;

    // Workspace layout: xp (B*N*64 f32) | e_src (B*N) | e_dst (B*N)  ~4.2 MB
    float* xp    = (float*)d_ws;
    float* e_src = xp + (size_t)BB * NN * DOUT;
    float* e_dst = e_src + (size_t)BB * NN;

    gat_xp_kernel<<<(BB * NN) / 16, 256, 0, stream>>>(x, W, bvec, a, xp, e_src, e_dst);
    gat_attn_kernel<<<BB * NN, 256, 0, stream>>>(adj, xp, e_src, e_dst, out);
}